// Round 11
// baseline (675.171 us; speedup 1.0000x reference)
//
#include <hip/hip_runtime.h>
#include <hip/hip_bf16.h>
#include <math.h>

#define NB 4096   // batch
#define ND 2048   // feature dim
#define BT 256    // output tile (256x256)
#define NTB (NB / BT)     // 16 tile-blocks per dim
#define NKT (ND / 32)     // 64 K-tiles of 32
#define TPC 68            // transposed-pack padded row (ushorts), 64-row chunks

typedef __attribute__((ext_vector_type(8))) short short8;
typedef __attribute__((ext_vector_type(4))) float floatx4;
typedef __attribute__((ext_vector_type(4))) unsigned short ushort4v;

#define GLOAD_LDS16(g, l) \
  __builtin_amdgcn_global_load_lds((const __attribute__((address_space(1))) void*)(g), \
                                   (__attribute__((address_space(3))) void*)(l), 16, 0, 0)

// order-preserving float<->uint encode (min/max via unsigned atomics)
__device__ __forceinline__ unsigned fenc(float f) {
  unsigned u = __float_as_uint(f);
  return (u >> 31) ? ~u : (u | 0x80000000u);
}
__device__ __forceinline__ float fdec(unsigned u) {
  unsigned b = (u & 0x80000000u) ? (u ^ 0x80000000u) : ~u;
  return __uint_as_float(b);
}

__device__ __forceinline__ unsigned f2bf(float x) {  // RNE fp32 -> bf16 bits
  unsigned u = __float_as_uint(x);
  return (u + 0x7FFFu + ((u >> 16) & 1u)) >> 16;
}

union H16 { unsigned short u; _Float16 h; };
__device__ __forceinline__ unsigned short f2h(float x) { H16 c; c.h = (_Float16)x; return c.u; }
__device__ __forceinline__ float h2f(unsigned short u) { H16 c; c.u = u; return (float)c.h; }

// ---- kernel 1: L2-normalize rows -> bf16; init min/max sentinels ----
__global__ __launch_bounds__(256) void norm_kernel(const float* __restrict__ feats,
                                                   unsigned short* __restrict__ fb,
                                                   unsigned* __restrict__ gpm,
                                                   unsigned* __restrict__ gnm) {
  int row = blockIdx.x;
  int t = threadIdx.x;
  if (t == 0) {
    gpm[row] = 0xFFFFFFFFu;  // decodes NaN -> masks false (empty-min semantics)
    gnm[row] = 0u;
  }
  const float4* src = (const float4*)(feats + (size_t)row * ND);
  float4 v0 = src[t * 2];
  float4 v1 = src[t * 2 + 1];
  float ss = v0.x * v0.x + v0.y * v0.y + v0.z * v0.z + v0.w * v0.w +
             v1.x * v1.x + v1.y * v1.y + v1.z * v1.z + v1.w * v1.w;
  for (int off = 32; off > 0; off >>= 1) ss += __shfl_down(ss, off);
  __shared__ float wsum[4];
  int lane = t & 63, wid = t >> 6;
  if (lane == 0) wsum[wid] = ss;
  __syncthreads();
  float tot = wsum[0] + wsum[1] + wsum[2] + wsum[3];
  float inv = 1.0f / (sqrtf(tot) + 1e-12f);
  uint4 o;
  o.x = f2bf(v0.x * inv) | (f2bf(v0.y * inv) << 16);
  o.y = f2bf(v0.z * inv) | (f2bf(v0.w * inv) << 16);
  o.z = f2bf(v1.x * inv) | (f2bf(v1.y * inv) << 16);
  o.w = f2bf(v1.z * inv) | (f2bf(v1.w * inv) << 16);
  ((uint4*)(fb + (size_t)row * ND))[t] = o;
}

// ---- kernel 2: 256x256-tile 8-wave GEMM; BK=32, 2-deep dbuf, 2 blocks/CU ----
__global__ __launch_bounds__(512, 4) void pass0_kernel(const unsigned short* __restrict__ fb,
                                                       const int* __restrict__ labels,
                                                       unsigned* __restrict__ gpm,
                                                       unsigned* __restrict__ gnm,
                                                       unsigned short* __restrict__ sim) {
  // 2 slots x (A 16KB + B 16KB) = 64KB; epilogue pack (35KB) reuses region.
  // Total static LDS ~68KB -> 2 blocks/CU (16 waves, 4/SIMD).
  __shared__ __align__(16) char shraw[65536];
  __shared__ int rowlab[BT], collab[BT];

  int tid = threadIdx.x;
  int l = tid & 63, wv = tid >> 6;
  int wm = wv >> 2, wn = wv & 3;   // 2 x 4 wave grid

  // XCD clustering: each XCD owns a 4(bi) x 8(bj) rectangle
  int bid = blockIdx.x;
  int xcd = bid & 7, li_ = bid >> 3;
  int bi = (xcd >> 1) * 4 + (li_ >> 3);
  int bj = (xcd & 1) * 8 + (li_ & 7);
  int row0 = bi * BT, col0 = bj * BT;

  char* A0p = shraw;
  char* B0p = shraw + 16384;
  char* A1p = shraw + 32768;
  char* B1p = shraw + 49152;

  // stage one 256x32 A-tile + B-tile (2+2 gloads/thread): linear LDS dest,
  // inverse-swizzled global source; chunk swizzle (r>>1)&3 (2-way-only banks)
  auto stageT = [&](char* SA, char* SB, int ts) {
#pragma unroll
    for (int e = 0; e < 2; e++) {
      int li = e * 512 + tid;              // 0..1023
      int r_ = li >> 2, c_ = li & 3;
      int gk = ts * 32 + ((c_ ^ ((r_ >> 1) & 3)) * 8);
      GLOAD_LDS16(fb + (size_t)(row0 + r_) * ND + gk, SA + li * 16);
      GLOAD_LDS16(fb + (size_t)(col0 + r_) * ND + gk, SB + li * 16);
    }
  };

  floatx4 acc[8][4];
#pragma unroll
  for (int j = 0; j < 8; j++)
#pragma unroll
    for (int r = 0; r < 4; r++) acc[j][r] = (floatx4){0.f, 0.f, 0.f, 0.f};

  // per-lane LDS byte offsets (row stride 64B; swizzled 16B chunk)
  int offA[8], offB[4];
  {
    int ck = l >> 4;
#pragma unroll
    for (int j = 0; j < 8; j++) {
      int rh = (2 * j + wm) * 16 + (l & 15);
      offA[j] = rh * 64 + ((ck ^ ((rh >> 1) & 3)) * 16);
    }
#pragma unroll
    for (int r = 0; r < 4; r++) {
      int rh = (wn + 4 * r) * 16 + (l & 15);
      offB[r] = rh * 64 + ((ck ^ ((rh >> 1) & 3)) * 16);
    }
  }

  // clean vmcnt ledger: labels drained before any stage
  if (tid < BT) {
    rowlab[tid] = labels[row0 + tid];
    collab[tid] = labels[col0 + tid];
  }
  asm volatile("s_waitcnt vmcnt(0) lgkmcnt(0)" ::: "memory");
  __builtin_amdgcn_s_barrier();

  // prologue: tile0 resident
  stageT(A0p, B0p, 0);
  asm volatile("s_waitcnt vmcnt(0)" ::: "memory");
  __builtin_amdgcn_s_barrier();

  // per tile: stage(u+1) -> 12 ds_reads -> lgkm(0) -> 32 MFMA -> vmcnt(0) -> barrier
#pragma unroll 2
  for (int u = 0; u < NKT; u++) {
    const char* AP = (u & 1) ? A1p : A0p;
    const char* BP = (u & 1) ? B1p : B0p;
    char* SA = (u & 1) ? A0p : A1p;
    char* SB = (u & 1) ? B0p : B1p;
    bool more = (u + 1 < NKT);
    if (more) stageT(SA, SB, u + 1);
    short8 a_[8], b_[4];
#pragma unroll
    for (int j = 0; j < 8; j++) a_[j] = *(const short8*)(AP + offA[j]);
#pragma unroll
    for (int r = 0; r < 4; r++) b_[r] = *(const short8*)(BP + offB[r]);
    asm volatile("s_waitcnt lgkmcnt(0)" ::: "memory");
    __builtin_amdgcn_sched_barrier(0);
    __builtin_amdgcn_s_setprio(1);
#pragma unroll
    for (int j = 0; j < 8; j++)
#pragma unroll
      for (int r = 0; r < 4; r++)
        acc[j][r] = __builtin_amdgcn_mfma_f32_16x16x32_bf16(a_[j], b_[r], acc[j][r], 0, 0, 0);
    __builtin_amdgcn_s_setprio(0);
    if (more) asm volatile("s_waitcnt vmcnt(0)" ::: "memory");
    __builtin_amdgcn_s_barrier();
  }

  // ---- row-attributed stats from registers ----
  // C/D layout: col = lane&15, row = (lane>>4)*4 + v; frag row = (2j+wm)*16
#pragma unroll
  for (int j = 0; j < 8; j++) {
#pragma unroll
    for (int v = 0; v < 4; v++) {
      int row_l = (2 * j + wm) * 16 + (l >> 4) * 4 + v;
      int grow = row0 + row_l;
      int rl = rowlab[row_l];
      float pmin = 3.0e38f, nmax = -3.0e38f;
#pragma unroll
      for (int r = 0; r < 4; r++) {
        int col_l = (wn + 4 * r) * 16 + (l & 15);
        float s = acc[j][r][v];
        if (rl == collab[col_l]) {
          if ((col0 + col_l) != grow && s < 0.99999f) pmin = fminf(pmin, s);
        } else {
          nmax = fmaxf(nmax, s);
        }
      }
#pragma unroll
      for (int off = 1; off < 16; off <<= 1) {
        pmin = fminf(pmin, __shfl_xor(pmin, off));
        nmax = fmaxf(nmax, __shfl_xor(nmax, off));
      }
      if ((l & 15) == 0) {
        atomicMin(&gpm[grow], fenc(pmin));  // sentinels encode harmless
        atomicMax(&gnm[grow], fenc(nmax));
      }
    }
  }

  // ---- transposed fp16 pack + coalesced store, 4 chunks of 64 orig-rows ----
#pragma unroll
  for (int h = 0; h < 4; h++) {
    __syncthreads();  // previous LDS use done
    unsigned short (*tileT)[TPC] = (unsigned short(*)[TPC])shraw;
#pragma unroll
    for (int jl = 0; jl < 2; jl++) {
      int j = h * 2 + jl;                         // acc row-block in this chunk
      int lr = 32 * jl + wm * 16 + (l >> 4) * 4;  // local row within chunk (0..63)
#pragma unroll
      for (int r = 0; r < 4; r++) {
        int C = (wn + 4 * r) * 16 + (l & 15);
        ushort4v pk;
        pk[0] = f2h(acc[j][r][0]);
        pk[1] = f2h(acc[j][r][1]);
        pk[2] = f2h(acc[j][r][2]);
        pk[3] = f2h(acc[j][r][3]);
        *(ushort4v*)(&tileT[C][lr]) = pk;
      }
    }
    __syncthreads();
    int c = tid >> 1, seg = tid & 1;
    const unsigned short* srcp = &tileT[c][seg * 32];
    unsigned short* dstp = sim + (size_t)(col0 + c) * NB + row0 + h * 64 + seg * 32;
#pragma unroll
    for (int k = 0; k < 4; k++)
      *(short8*)(dstp + k * 8) = *(const short8*)(srcp + k * 8);
  }
}

// ---- kernel 3: streaming masked exp-sums, one wave per row ----
__global__ __launch_bounds__(256) void sums_kernel(const unsigned short* __restrict__ sim,
                                                   const int* __restrict__ labels,
                                                   const unsigned* __restrict__ gpm,
                                                   const unsigned* __restrict__ gnm,
                                                   float* __restrict__ gps,
                                                   float* __restrict__ gns) {
  int t = threadIdx.x, l = t & 63, w = t >> 6;
  int r = blockIdx.x * 4 + w;
  int rl = labels[r];
  float pm = fdec(gpm[r]);  // pos_min (NaN if none -> masks false)
  float nm = fdec(gnm[r]);  // neg_max
  const unsigned short* row = sim + (size_t)r * NB;
  float ps0 = 0.f, ps1 = 0.f, ns0 = 0.f, ns1 = 0.f;
#pragma unroll
  for (int it = 0; it < 8; it++) {
    int j0 = it * 512 + l * 8;
    short8 sv = *(const short8*)(row + j0);
    int4 lb0 = *(const int4*)(labels + j0);
    int4 lb1 = *(const int4*)(labels + j0 + 4);
    int lb[8] = {lb0.x, lb0.y, lb0.z, lb0.w, lb1.x, lb1.y, lb1.z, lb1.w};
#pragma unroll
    for (int e = 0; e < 8; e++) {
      float s = h2f((unsigned short)sv[e]);
      int j = j0 + e;
      float pv = 0.f, nv = 0.f;
      if (lb[e] == rl) {
        if (j != r && s < 0.99999f && (s - 0.1f < nm)) pv = __expf(-2.0f * (s - 0.5f));
      } else {
        if (s + 0.1f > pm) nv = __expf(40.0f * (s - 0.5f));
      }
      if (e & 1) { ps1 += pv; ns1 += nv; }
      else       { ps0 += pv; ns0 += nv; }
    }
  }
  float ps = ps0 + ps1, ns = ns0 + ns1;
  for (int off = 32; off > 0; off >>= 1) {
    ps += __shfl_down(ps, off);
    ns += __shfl_down(ns, off);
  }
  if (l == 0) { gps[r] = ps; gns[r] = ns; }
}

// ---- kernel 4: finalize scalar loss ----
__global__ __launch_bounds__(256) void finalize_kernel(const float* __restrict__ gps,
                                                       const float* __restrict__ gns,
                                                       float* __restrict__ out) {
  int t = threadIdx.x;
  float sum = 0.f;
  for (int i = t; i < NB; i += 256) {
    float ps = gps[i], ns = gns[i];
    if (ps > 0.f && ns > 0.f) sum += 0.5f * log1pf(ps) + 0.025f * log1pf(ns);
  }
  for (int off = 32; off > 0; off >>= 1) sum += __shfl_down(sum, off);
  __shared__ float wsum[4];
  int lane = t & 63, wid = t >> 6;
  if (lane == 0) wsum[wid] = sum;
  __syncthreads();
  if (t == 0) out[0] = (wsum[0] + wsum[1] + wsum[2] + wsum[3]) / (float)NB;
}

extern "C" void kernel_launch(void* const* d_in, const int* in_sizes, int n_in,
                              void* d_out, int out_size, void* d_ws, size_t ws_size,
                              hipStream_t stream) {
  const float* feats = (const float*)d_in[0];
  const int* labels = (const int*)d_in[1];

  char* ws = (char*)d_ws;
  unsigned short* fb = (unsigned short*)ws;                  // 16 MB bf16 normalized feats
  size_t off = (size_t)NB * ND * 2;
  unsigned short* sim = (unsigned short*)(ws + off);         // 32 MB fp16 sim (full)
  off += (size_t)NB * NB * 2;
  unsigned* gpm = (unsigned*)(ws + off); off += NB * 4;
  unsigned* gnm = (unsigned*)(ws + off); off += NB * 4;
  float* gps = (float*)(ws + off); off += NB * 4;
  float* gns = (float*)(ws + off); off += NB * 4;

  norm_kernel<<<NB, 256, 0, stream>>>(feats, fb, gpm, gnm);
  pass0_kernel<<<NTB * NTB, 512, 0, stream>>>(fb, labels, gpm, gnm, sim);
  sums_kernel<<<NB / 4, 256, 0, stream>>>(sim, labels, gpm, gnm, gps, gns);
  finalize_kernel<<<1, 256, 0, stream>>>(gps, gns, (float*)d_out);
}

// Round 12
// 132.729 us; speedup vs baseline: 5.0868x; 5.0868x over previous
//
#include <hip/hip_runtime.h>
#include <hip/hip_bf16.h>
#include <math.h>

#define NB 4096   // batch
#define ND 2048   // feature dim
#define BT 128    // output tile (128x128)
#define NTB (NB / BT)     // 32 tile-blocks per dim
#define NKT (ND / 64)     // 32 K-tiles of 64
#define TPC 68            // transposed-pack padded row (ushorts), 64-row chunks

typedef __attribute__((ext_vector_type(8))) short short8;
typedef __attribute__((ext_vector_type(4))) float floatx4;
typedef __attribute__((ext_vector_type(4))) unsigned short ushort4v;

#define GLOAD_LDS16(g, l) \
  __builtin_amdgcn_global_load_lds((const __attribute__((address_space(1))) void*)(g), \
                                   (__attribute__((address_space(3))) void*)(l), 16, 0, 0)

// order-preserving float<->uint encode (min/max via unsigned atomics)
__device__ __forceinline__ unsigned fenc(float f) {
  unsigned u = __float_as_uint(f);
  return (u >> 31) ? ~u : (u | 0x80000000u);
}
__device__ __forceinline__ float fdec(unsigned u) {
  unsigned b = (u & 0x80000000u) ? (u ^ 0x80000000u) : ~u;
  return __uint_as_float(b);
}

__device__ __forceinline__ unsigned f2bf(float x) {  // RNE fp32 -> bf16 bits
  unsigned u = __float_as_uint(x);
  return (u + 0x7FFFu + ((u >> 16) & 1u)) >> 16;
}

union H16 { unsigned short u; _Float16 h; };
__device__ __forceinline__ unsigned short f2h(float x) { H16 c; c.h = (_Float16)x; return c.u; }
__device__ __forceinline__ float h2f(unsigned short u) { H16 c; c.u = u; return (float)c.h; }

// ---- kernel 1: L2-normalize rows -> bf16; init min/max sentinels ----
__global__ __launch_bounds__(256) void norm_kernel(const float* __restrict__ feats,
                                                   unsigned short* __restrict__ fb,
                                                   unsigned* __restrict__ gpm,
                                                   unsigned* __restrict__ gnm) {
  int row = blockIdx.x;
  int t = threadIdx.x;
  if (t == 0) {
    gpm[row] = 0xFFFFFFFFu;  // decodes NaN -> masks false (empty-min semantics)
    gnm[row] = 0u;
  }
  const float4* src = (const float4*)(feats + (size_t)row * ND);
  float4 v0 = src[t * 2];
  float4 v1 = src[t * 2 + 1];
  float ss = v0.x * v0.x + v0.y * v0.y + v0.z * v0.z + v0.w * v0.w +
             v1.x * v1.x + v1.y * v1.y + v1.z * v1.z + v1.w * v1.w;
  for (int off = 32; off > 0; off >>= 1) ss += __shfl_down(ss, off);
  __shared__ float wsum[4];
  int lane = t & 63, wid = t >> 6;
  if (lane == 0) wsum[wid] = ss;
  __syncthreads();
  float tot = wsum[0] + wsum[1] + wsum[2] + wsum[3];
  float inv = 1.0f / (sqrtf(tot) + 1e-12f);
  uint4 o;
  o.x = f2bf(v0.x * inv) | (f2bf(v0.y * inv) << 16);
  o.y = f2bf(v0.z * inv) | (f2bf(v0.w * inv) << 16);
  o.z = f2bf(v1.x * inv) | (f2bf(v1.y * inv) << 16);
  o.w = f2bf(v1.z * inv) | (f2bf(v1.w * inv) << 16);
  ((uint4*)(fb + (size_t)row * ND))[t] = o;
}

// ---- kernel 2: m97-geometry GEMM: 128x128 tile, 4 waves, BK=64, 3 blocks/CU ----
__global__ __launch_bounds__(256, 3) void pass0_kernel(const unsigned short* __restrict__ fb,
                                                       const int* __restrict__ labels,
                                                       unsigned* __restrict__ gpm,
                                                       unsigned* __restrict__ gnm,
                                                       unsigned short* __restrict__ sim) {
  // A [128][64] + B [128][64] bf16 = 32KB single-buffered; pack reuses region
  __shared__ __align__(16) char shraw[32768];
  __shared__ int rowlab[BT], collab[BT];

  int tid = threadIdx.x;
  int l = tid & 63, wv = tid >> 6;
  int wr = wv >> 1, wc = wv & 1;   // 2 x 2 wave grid, each 64x64

  // XCD clustering: each XCD owns an 8(bi) x 16(bj) rectangle of the 32x32 grid
  int bid = blockIdx.x;
  int xcd = bid & 7, li_ = bid >> 3;          // li_ 0..127
  int bi = (xcd >> 1) * 8 + (li_ >> 4);
  int bj = (xcd & 1) * 16 + (li_ & 15);
  int row0 = bi * BT, col0 = bj * BT;

  unsigned short* As = (unsigned short*)shraw;            // [128*64]
  unsigned short* Bs = (unsigned short*)(shraw + 16384);

  // stage K-tile ts: 1024 chunks each; linear LDS dest, slot c_ holds global
  // chunk (c_ ^ (r_&7))  [both-sides involution]
  auto stageT = [&](int ts) {
#pragma unroll
    for (int e = 0; e < 4; e++) {
      int li = e * 256 + tid;          // 0..1023
      int r_ = li >> 3, c_ = li & 7;
      int gk = ts * 64 + ((c_ ^ (r_ & 7)) * 8);
      GLOAD_LDS16(fb + (size_t)(row0 + r_) * ND + gk, (char*)As + li * 16);
      GLOAD_LDS16(fb + (size_t)(col0 + r_) * ND + gk, (char*)Bs + li * 16);
    }
  };

  floatx4 acc[4][4];
#pragma unroll
  for (int j = 0; j < 4; j++)
#pragma unroll
    for (int r = 0; r < 4; r++) acc[j][r] = (floatx4){0.f, 0.f, 0.f, 0.f};

  // single per-thread base; frag (j, s) at base + j*2048 + s*64
  // (slot = ck ^ (row&7); row&7 = (l&15)&7 indep. of j; ck = s*4 + (l>>4))
  int baseA = (wr * 64 + (l & 15)) * 128 + (((l >> 4) ^ ((l & 15) & 7)) * 16);
  int baseB = (wc * 64 + (l & 15)) * 128 + (((l >> 4) ^ ((l & 15) & 7)) * 16);

  if (tid < BT) {
    rowlab[tid] = labels[row0 + tid];
    collab[tid] = labels[col0 + tid];
  }
  __syncthreads();

  for (int u = 0; u < NKT; u++) {
    stageT(u);
    __syncthreads();   // drains vmcnt: tile resident for all waves
    short8 a_[4][2], b_[4][2];
#pragma unroll
    for (int j = 0; j < 4; j++) {
      a_[j][0] = *(const short8*)((const char*)As + baseA + j * 2048);
      a_[j][1] = *(const short8*)((const char*)As + baseA + j * 2048 + 64);
    }
#pragma unroll
    for (int r = 0; r < 4; r++) {
      b_[r][0] = *(const short8*)((const char*)Bs + baseB + r * 2048);
      b_[r][1] = *(const short8*)((const char*)Bs + baseB + r * 2048 + 64);
    }
#pragma unroll
    for (int j = 0; j < 4; j++)
#pragma unroll
      for (int r = 0; r < 4; r++) {
        acc[j][r] = __builtin_amdgcn_mfma_f32_16x16x32_bf16(a_[j][0], b_[r][0], acc[j][r], 0, 0, 0);
        acc[j][r] = __builtin_amdgcn_mfma_f32_16x16x32_bf16(a_[j][1], b_[r][1], acc[j][r], 0, 0, 0);
      }
    __syncthreads();   // all reads done before next stage overwrites
  }

  // ---- row-attributed stats from registers ----
  // C/D layout: col = lane&15, row = (lane>>4)*4 + v; frag row = wr*64 + j*16
#pragma unroll
  for (int j = 0; j < 4; j++) {
#pragma unroll
    for (int v = 0; v < 4; v++) {
      int row_l = wr * 64 + j * 16 + (l >> 4) * 4 + v;
      int grow = row0 + row_l;
      int rl = rowlab[row_l];
      float pmin = 3.0e38f, nmax = -3.0e38f;
#pragma unroll
      for (int r = 0; r < 4; r++) {
        int col_l = wc * 64 + r * 16 + (l & 15);
        float s = acc[j][r][v];
        if (rl == collab[col_l]) {
          if ((col0 + col_l) != grow && s < 0.99999f) pmin = fminf(pmin, s);
        } else {
          nmax = fmaxf(nmax, s);
        }
      }
#pragma unroll
      for (int off = 1; off < 16; off <<= 1) {
        pmin = fminf(pmin, __shfl_xor(pmin, off));
        nmax = fmaxf(nmax, __shfl_xor(nmax, off));
      }
      if ((l & 15) == 0) {
        atomicMin(&gpm[grow], fenc(pmin));  // sentinels encode harmless
        atomicMax(&gnm[grow], fenc(nmax));
      }
    }
  }

  // ---- transposed fp16 pack + coalesced store, 2 chunks of 64 orig-rows ----
#pragma unroll
  for (int h = 0; h < 2; h++) {
    __syncthreads();  // previous LDS use done
    unsigned short (*tileT)[TPC] = (unsigned short(*)[TPC])shraw;
    if (wr == h) {
#pragma unroll
      for (int j = 0; j < 4; j++) {
        int lr = j * 16 + (l >> 4) * 4;  // local row within chunk (0..63)
#pragma unroll
        for (int r = 0; r < 4; r++) {
          int C = wc * 64 + r * 16 + (l & 15);
          ushort4v pk;
          pk[0] = f2h(acc[j][r][0]);
          pk[1] = f2h(acc[j][r][1]);
          pk[2] = f2h(acc[j][r][2]);
          pk[3] = f2h(acc[j][r][3]);
          *(ushort4v*)(&tileT[C][lr]) = pk;
        }
      }
    }
    __syncthreads();
    int c = tid >> 1, seg = tid & 1;
    const unsigned short* srcp = &tileT[c][seg * 32];
    unsigned short* dstp = sim + (size_t)(col0 + c) * NB + row0 + h * 64 + seg * 32;
#pragma unroll
    for (int k = 0; k < 4; k++)
      *(short8*)(dstp + k * 8) = *(const short8*)(srcp + k * 8);
  }
}

// ---- kernel 3: streaming masked exp-sums, one wave per row ----
__global__ __launch_bounds__(256) void sums_kernel(const unsigned short* __restrict__ sim,
                                                   const int* __restrict__ labels,
                                                   const unsigned* __restrict__ gpm,
                                                   const unsigned* __restrict__ gnm,
                                                   float* __restrict__ gps,
                                                   float* __restrict__ gns) {
  int t = threadIdx.x, l = t & 63, w = t >> 6;
  int r = blockIdx.x * 4 + w;
  int rl = labels[r];
  float pm = fdec(gpm[r]);  // pos_min (NaN if none -> masks false)
  float nm = fdec(gnm[r]);  // neg_max
  const unsigned short* row = sim + (size_t)r * NB;
  float ps0 = 0.f, ps1 = 0.f, ns0 = 0.f, ns1 = 0.f;
#pragma unroll
  for (int it = 0; it < 8; it++) {
    int j0 = it * 512 + l * 8;
    short8 sv = *(const short8*)(row + j0);
    int4 lb0 = *(const int4*)(labels + j0);
    int4 lb1 = *(const int4*)(labels + j0 + 4);
    int lb[8] = {lb0.x, lb0.y, lb0.z, lb0.w, lb1.x, lb1.y, lb1.z, lb1.w};
#pragma unroll
    for (int e = 0; e < 8; e++) {
      float s = h2f((unsigned short)sv[e]);
      int j = j0 + e;
      float pv = 0.f, nv = 0.f;
      if (lb[e] == rl) {
        if (j != r && s < 0.99999f && (s - 0.1f < nm)) pv = __expf(-2.0f * (s - 0.5f));
      } else {
        if (s + 0.1f > pm) nv = __expf(40.0f * (s - 0.5f));
      }
      if (e & 1) { ps1 += pv; ns1 += nv; }
      else       { ps0 += pv; ns0 += nv; }
    }
  }
  float ps = ps0 + ps1, ns = ns0 + ns1;
  for (int off = 32; off > 0; off >>= 1) {
    ps += __shfl_down(ps, off);
    ns += __shfl_down(ns, off);
  }
  if (l == 0) { gps[r] = ps; gns[r] = ns; }
}

// ---- kernel 4: finalize scalar loss ----
__global__ __launch_bounds__(256) void finalize_kernel(const float* __restrict__ gps,
                                                       const float* __restrict__ gns,
                                                       float* __restrict__ out) {
  int t = threadIdx.x;
  float sum = 0.f;
  for (int i = t; i < NB; i += 256) {
    float ps = gps[i], ns = gns[i];
    if (ps > 0.f && ns > 0.f) sum += 0.5f * log1pf(ps) + 0.025f * log1pf(ns);
  }
  for (int off = 32; off > 0; off >>= 1) sum += __shfl_down(sum, off);
  __shared__ float wsum[4];
  int lane = t & 63, wid = t >> 6;
  if (lane == 0) wsum[wid] = sum;
  __syncthreads();
  if (t == 0) out[0] = (wsum[0] + wsum[1] + wsum[2] + wsum[3]) / (float)NB;
}

extern "C" void kernel_launch(void* const* d_in, const int* in_sizes, int n_in,
                              void* d_out, int out_size, void* d_ws, size_t ws_size,
                              hipStream_t stream) {
  const float* feats = (const float*)d_in[0];
  const int* labels = (const int*)d_in[1];

  char* ws = (char*)d_ws;
  unsigned short* fb = (unsigned short*)ws;                  // 16 MB bf16 normalized feats
  size_t off = (size_t)NB * ND * 2;
  unsigned short* sim = (unsigned short*)(ws + off);         // 32 MB fp16 sim (full)
  off += (size_t)NB * NB * 2;
  unsigned* gpm = (unsigned*)(ws + off); off += NB * 4;
  unsigned* gnm = (unsigned*)(ws + off); off += NB * 4;
  float* gps = (float*)(ws + off); off += NB * 4;
  float* gns = (float*)(ws + off); off += NB * 4;

  norm_kernel<<<NB, 256, 0, stream>>>(feats, fb, gpm, gnm);
  pass0_kernel<<<NTB * NTB, 256, 0, stream>>>(fb, labels, gpm, gnm, sim);
  sums_kernel<<<NB / 4, 256, 0, stream>>>(sim, labels, gpm, gnm, gps, gns);
  finalize_kernel<<<1, 256, 0, stream>>>(gps, gns, (float*)d_out);
}

// Round 14
// 112.200 us; speedup vs baseline: 6.0176x; 1.1830x over previous
//
#include <hip/hip_runtime.h>
#include <hip/hip_bf16.h>
#include <math.h>

#define NB 4096   // batch
#define ND 2048   // feature dim
#define BT 128    // output tile (128x128)
#define NTB (NB / BT)            // 32 tile-blocks per dim
#define NBLK (NTB * (NTB + 1) / 2)  // 528 upper-tri blocks
#define NKT (ND / 64)            // 32 K-tiles of 64
#define TPC 68                   // padded pack row (ushorts)

typedef __attribute__((ext_vector_type(8))) short short8;
typedef __attribute__((ext_vector_type(4))) float floatx4;
typedef __attribute__((ext_vector_type(4))) unsigned short ushort4v;

#define GLOAD_LDS16(g, l) \
  __builtin_amdgcn_global_load_lds((const __attribute__((address_space(1))) void*)(g), \
                                   (__attribute__((address_space(3))) void*)(l), 16, 0, 0)

__device__ __forceinline__ unsigned f2bf(float x) {  // RNE fp32 -> bf16 bits
  unsigned u = __float_as_uint(x);
  return (u + 0x7FFFu + ((u >> 16) & 1u)) >> 16;
}

union H16 { unsigned short u; _Float16 h; };
__device__ __forceinline__ unsigned short f2h(float x) { H16 c; c.h = (_Float16)x; return c.u; }
__device__ __forceinline__ float h2f(unsigned short u) { H16 c; c.u = u; return (float)c.h; }

// ---- kernel 1: L2-normalize rows -> bf16 ----
__global__ __launch_bounds__(256) void norm_kernel(const float* __restrict__ feats,
                                                   unsigned short* __restrict__ fb) {
  int row = blockIdx.x;
  int t = threadIdx.x;
  const float4* src = (const float4*)(feats + (size_t)row * ND);
  float4 v0 = src[t * 2];
  float4 v1 = src[t * 2 + 1];
  float ss = v0.x * v0.x + v0.y * v0.y + v0.z * v0.z + v0.w * v0.w +
             v1.x * v1.x + v1.y * v1.y + v1.z * v1.z + v1.w * v1.w;
  for (int off = 32; off > 0; off >>= 1) ss += __shfl_down(ss, off);
  __shared__ float wsum[4];
  int lane = t & 63, wid = t >> 6;
  if (lane == 0) wsum[wid] = ss;
  __syncthreads();
  float tot = wsum[0] + wsum[1] + wsum[2] + wsum[3];
  float inv = 1.0f / (sqrtf(tot) + 1e-12f);
  uint4 o;
  o.x = f2bf(v0.x * inv) | (f2bf(v0.y * inv) << 16);
  o.y = f2bf(v0.z * inv) | (f2bf(v0.w * inv) << 16);
  o.z = f2bf(v1.x * inv) | (f2bf(v1.y * inv) << 16);
  o.w = f2bf(v1.z * inv) | (f2bf(v1.w * inv) << 16);
  ((uint4*)(fb + (size_t)row * ND))[t] = o;
}

// ---- kernel 2: triangular 128x128-tile GEMM, dbuf BK=64, dual store ----
__global__ __launch_bounds__(256) void pass0_kernel(const unsigned short* __restrict__ fb,
                                                    unsigned short* __restrict__ sim) {
  // 2 x (A 16KB + B 16KB) = 64KB; epilogue packs (17.4KB) reuse the region
  __shared__ __align__(16) char shraw[65536];

  int tid = threadIdx.x;
  int l = tid & 63, wv = tid >> 6;
  int wr = wv >> 1, wc = wv & 1;   // 2 x 2 wave grid, each 64x64

  // upper-triangular block decode: row bi has (NTB - bi) blocks
  int rem = blockIdx.x, bi = 0;
  while (rem >= NTB - bi) { rem -= NTB - bi; bi++; }
  int bj = bi + rem;
  int row0 = bi * BT, col0 = bj * BT;

  unsigned short* As0 = (unsigned short*)shraw;
  unsigned short* Bs0 = (unsigned short*)(shraw + 16384);
  unsigned short* As1 = (unsigned short*)(shraw + 32768);
  unsigned short* Bs1 = (unsigned short*)(shraw + 49152);

  // stage K-tile ts: linear LDS dest; LDS slot c_ holds global chunk c_ ^ (r_&7)
  auto stageT = [&](unsigned short* SA, unsigned short* SB, int ts) {
#pragma unroll
    for (int e = 0; e < 4; e++) {
      int li = e * 256 + tid;          // 0..1023
      int r_ = li >> 3, c_ = li & 7;
      int gk = ts * 64 + ((c_ ^ (r_ & 7)) * 8);
      GLOAD_LDS16(fb + (size_t)(row0 + r_) * ND + gk, (char*)SA + li * 16);
      GLOAD_LDS16(fb + (size_t)(col0 + r_) * ND + gk, (char*)SB + li * 16);
    }
  };

  floatx4 acc[4][4];
#pragma unroll
  for (int j = 0; j < 4; j++)
#pragma unroll
    for (int r = 0; r < 4; r++) acc[j][r] = (floatx4){0.f, 0.f, 0.f, 0.f};

  // R6-R8-verified explicit fragment offsets: slot = (s*4 + (l>>4)) ^ (row&7)
  int offA[4][2], offB[4][2];
#pragma unroll
  for (int j = 0; j < 4; j++) {
    int rh = wr * 64 + j * 16 + (l & 15);
#pragma unroll
    for (int s = 0; s < 2; s++) {
      int ck = s * 4 + (l >> 4);
      offA[j][s] = rh * 128 + ((ck ^ (rh & 7)) * 16);
    }
  }
#pragma unroll
  for (int r = 0; r < 4; r++) {
    int rh = wc * 64 + r * 16 + (l & 15);
#pragma unroll
    for (int s = 0; s < 2; s++) {
      int ck = s * 4 + (l >> 4);
      offB[r][s] = rh * 128 + ((ck ^ (rh & 7)) * 16);
    }
  }

  // prologue: tile0 resident
  stageT(As0, Bs0, 0);
  __syncthreads();

#pragma unroll 2
  for (int u = 0; u < NKT; u++) {
    const char* AP = (const char*)((u & 1) ? As1 : As0);
    const char* BP = (const char*)((u & 1) ? Bs1 : Bs0);
    unsigned short* SA = (u & 1) ? As0 : As1;
    unsigned short* SB = (u & 1) ? Bs0 : Bs1;
    if (u + 1 < NKT) stageT(SA, SB, u + 1);   // overlap with reads+MFMA below
    short8 a_[4][2], b_[4][2];
#pragma unroll
    for (int j = 0; j < 4; j++) {
      a_[j][0] = *(const short8*)(AP + offA[j][0]);
      a_[j][1] = *(const short8*)(AP + offA[j][1]);
    }
#pragma unroll
    for (int r = 0; r < 4; r++) {
      b_[r][0] = *(const short8*)(BP + offB[r][0]);
      b_[r][1] = *(const short8*)(BP + offB[r][1]);
    }
#pragma unroll
    for (int j = 0; j < 4; j++)
#pragma unroll
      for (int r = 0; r < 4; r++) {
        acc[j][r] = __builtin_amdgcn_mfma_f32_16x16x32_bf16(a_[j][0], b_[r][0], acc[j][r], 0, 0, 0);
        acc[j][r] = __builtin_amdgcn_mfma_f32_16x16x32_bf16(a_[j][1], b_[r][1], acc[j][r], 0, 0, 0);
      }
    __syncthreads();   // drains vmcnt/lgkm: next tile resident, reads done
  }

  // element (row_l, col_l): row_l = wr*64 + j*16 + (l>>4)*4 + v,
  //                         col_l = wc*64 + r*16 + (l&15)

  // ---- C^T pack + store -> mirror block [col0, row0] (covers diagonal too) ----
#pragma unroll
  for (int h = 0; h < 2; h++) {
    __syncthreads();
    unsigned short (*tileT)[TPC] = (unsigned short(*)[TPC])shraw;
    if (wr == h) {
#pragma unroll
      for (int j = 0; j < 4; j++) {
        int lr = j * 16 + (l >> 4) * 4;   // local orig-row within chunk
#pragma unroll
        for (int r = 0; r < 4; r++) {
          int C = wc * 64 + r * 16 + (l & 15);
          ushort4v pk;
          pk[0] = f2h(acc[j][r][0]);
          pk[1] = f2h(acc[j][r][1]);
          pk[2] = f2h(acc[j][r][2]);
          pk[3] = f2h(acc[j][r][3]);
          *(ushort4v*)(&tileT[C][lr]) = pk;
        }
      }
    }
    __syncthreads();
    int c = tid >> 1, seg = tid & 1;
    const unsigned short* srcp = &tileT[c][seg * 32];
    unsigned short* dstp = sim + (size_t)(col0 + c) * NB + row0 + h * 64 + seg * 32;
#pragma unroll
    for (int k = 0; k < 4; k++)
      *(short8*)(dstp + k * 8) = *(const short8*)(srcp + k * 8);
  }

  // ---- direct pack + store -> own block [row0, col0] (off-diagonal only) ----
  if (bi != bj) {
#pragma unroll
    for (int h = 0; h < 2; h++) {
      __syncthreads();
      unsigned short (*tileR)[TPC] = (unsigned short(*)[TPC])shraw;
      if (wc == h) {
#pragma unroll
        for (int j = 0; j < 4; j++)
#pragma unroll
          for (int r = 0; r < 4; r++) {
            int row_l = wr * 64 + j * 16 + (l >> 4) * 4;
            int ch = r * 16 + (l & 15);   // col within chunk (wc==h)
#pragma unroll
            for (int v = 0; v < 4; v++)
              tileR[row_l + v][ch] = f2h(acc[j][r][v]);
          }
      }
      __syncthreads();
      int r_ = tid >> 1, seg = tid & 1;
      const unsigned short* srcp = &tileR[r_][seg * 32];
      unsigned short* dstp = sim + (size_t)(row0 + r_) * NB + col0 + h * 64 + seg * 32;
#pragma unroll
      for (int k = 0; k < 4; k++)
        *(short8*)(dstp + k * 8) = *(const short8*)(srcp + k * 8);
    }
  }
}

// ---- kernel 3: fused stats + masked exp-sums, one wave per row ----
__global__ __launch_bounds__(256) void sums_kernel(const unsigned short* __restrict__ sim,
                                                   const int* __restrict__ labels,
                                                   float* __restrict__ gps,
                                                   float* __restrict__ gns) {
  int t = threadIdx.x, l = t & 63, w = t >> 6;
  int r = blockIdx.x * 4 + w;
  int rl = labels[r];
  const unsigned short* row = sim + (size_t)r * NB;

  short8 sv[8];
  float pmin = 3.0e38f, nmax = -3.0e38f;
#pragma unroll
  for (int it = 0; it < 8; it++) {
    int j0 = it * 512 + l * 8;
    sv[it] = *(const short8*)(row + j0);
    int4 lb0 = *(const int4*)(labels + j0);
    int4 lb1 = *(const int4*)(labels + j0 + 4);
    int lb[8] = {lb0.x, lb0.y, lb0.z, lb0.w, lb1.x, lb1.y, lb1.z, lb1.w};
#pragma unroll
    for (int e = 0; e < 8; e++) {
      float s = h2f((unsigned short)sv[it][e]);
      int j = j0 + e;
      if (lb[e] == rl) {
        if (j != r && s < 0.99999f) pmin = fminf(pmin, s);
      } else {
        nmax = fmaxf(nmax, s);
      }
    }
  }
#pragma unroll
  for (int off = 1; off < 64; off <<= 1) {
    pmin = fminf(pmin, __shfl_xor(pmin, off));
    nmax = fmaxf(nmax, __shfl_xor(nmax, off));
  }
  // empty-mask semantics: pmin=3e38 -> s+0.1>pmin false -> ns=0 -> invalid;
  // nmax=-3e38 -> s-0.1<nmax false -> ps=0 -> invalid. Matches reference.

  float ps0 = 0.f, ps1 = 0.f, ns0 = 0.f, ns1 = 0.f;
#pragma unroll
  for (int it = 0; it < 8; it++) {
    int j0 = it * 512 + l * 8;
    int4 lb0 = *(const int4*)(labels + j0);
    int4 lb1 = *(const int4*)(labels + j0 + 4);
    int lb[8] = {lb0.x, lb0.y, lb0.z, lb0.w, lb1.x, lb1.y, lb1.z, lb1.w};
#pragma unroll
    for (int e = 0; e < 8; e++) {
      float s = h2f((unsigned short)sv[it][e]);
      int j = j0 + e;
      float pv = 0.f, nv = 0.f;
      if (lb[e] == rl) {
        if (j != r && s < 0.99999f && (s - 0.1f < nmax)) pv = __expf(-2.0f * (s - 0.5f));
      } else {
        if (s + 0.1f > pmin) nv = __expf(40.0f * (s - 0.5f));
      }
      if (e & 1) { ps1 += pv; ns1 += nv; }
      else       { ps0 += pv; ns0 += nv; }
    }
  }
  float ps = ps0 + ps1, ns = ns0 + ns1;
  for (int off = 32; off > 0; off >>= 1) {
    ps += __shfl_down(ps, off);
    ns += __shfl_down(ns, off);
  }
  if (l == 0) { gps[r] = ps; gns[r] = ns; }
}

// ---- kernel 4: finalize scalar loss ----
__global__ __launch_bounds__(256) void finalize_kernel(const float* __restrict__ gps,
                                                       const float* __restrict__ gns,
                                                       float* __restrict__ out) {
  int t = threadIdx.x;
  float sum = 0.f;
  for (int i = t; i < NB; i += 256) {
    float ps = gps[i], ns = gns[i];
    if (ps > 0.f && ns > 0.f) sum += 0.5f * log1pf(ps) + 0.025f * log1pf(ns);
  }
  for (int off = 32; off > 0; off >>= 1) sum += __shfl_down(sum, off);
  __shared__ float wsum[4];
  int lane = t & 63, wid = t >> 6;
  if (lane == 0) wsum[wid] = sum;
  __syncthreads();
  if (t == 0) out[0] = (wsum[0] + wsum[1] + wsum[2] + wsum[3]) / (float)NB;
}

extern "C" void kernel_launch(void* const* d_in, const int* in_sizes, int n_in,
                              void* d_out, int out_size, void* d_ws, size_t ws_size,
                              hipStream_t stream) {
  const float* feats = (const float*)d_in[0];
  const int* labels = (const int*)d_in[1];

  char* ws = (char*)d_ws;
  unsigned short* fb = (unsigned short*)ws;                  // 16 MB bf16 normalized feats
  size_t off = (size_t)NB * ND * 2;
  unsigned short* sim = (unsigned short*)(ws + off);         // 32 MB fp16 sim (full)
  off += (size_t)NB * NB * 2;
  float* gps = (float*)(ws + off); off += NB * 4;
  float* gns = (float*)(ws + off); off += NB * 4;

  norm_kernel<<<NB, 256, 0, stream>>>(feats, fb);
  pass0_kernel<<<NBLK, 256, 0, stream>>>(fb, sim);
  sums_kernel<<<NB / 4, 256, 0, stream>>>(sim, labels, gps, gns);
  finalize_kernel<<<1, 256, 0, stream>>>(gps, gns, (float*)d_out);
}